// Round 8
// baseline (5650.799 us; speedup 1.0000x reference)
//
#include <hip/hip_runtime.h>
#include <math.h>

#define TS 2048

typedef float f32x2 __attribute__((ext_vector_type(2)));
typedef _Float16 f16;
typedef _Float16 f16x2 __attribute__((ext_vector_type(2)));
typedef _Float16 f16x8 __attribute__((ext_vector_type(8)));

// x-tile column swizzle (f32): quarters padded to stride 24 -> conflict-free
#define SWZ(c) ((((c)>>4)*24) + ((c)&15))
#define RSTR 96

// LDS float offsets
#define XT0  0       // x tile 0: [64 t][96] f32
#define XT1  6144    // x tile 1
#define HF32 12288   // h f32 [2 layer][2 parity][64]
#define H16F 12544   // h f16 [2 layer][2 parity][64]  (128 floats worth)
#define SCRO 12672   // epilogue scratch
#define LDSF 12800

// Raw barrier: LDS-ordering only, NO vmcnt drain (stage prefetch stays in flight)
#define BAR() do { asm volatile("s_waitcnt lgkmcnt(0)" ::: "memory"); __builtin_amdgcn_s_barrier(); } while(0)

union F4 { float4 f4; f32x2 h[2]; };

__device__ __forceinline__ float sigmoidf_(float v){ return __builtin_amdgcn_rcpf(1.0f+__expf(-v)); }
__device__ __forceinline__ float tanhf_(float v){
  v = fminf(15.0f, fmaxf(-15.0f, v));
  const float e = __expf(2.0f*v);
  return (e-1.0f)*__builtin_amdgcn_rcpf(e+1.0f);
}
// quad (4-lane) sum via DPP quad_perm butterflies (VALU pipe)
__device__ __forceinline__ float qadd2(float v){
  float a = v + __int_as_float(__builtin_amdgcn_update_dpp(0, __float_as_int(v), 0xB1, 0xF, 0xF, true));
  return a + __int_as_float(__builtin_amdgcn_update_dpp(0, __float_as_int(a), 0x4E, 0xF, 0xF, true));
}
// full 64-lane sum via DPP row_shr scan + row_bcast, uniform via readlane(63)
__device__ __forceinline__ float wsum64(float v){
  v += __int_as_float(__builtin_amdgcn_update_dpp(0, __float_as_int(v), 0x111, 0xF, 0xF, true));
  v += __int_as_float(__builtin_amdgcn_update_dpp(0, __float_as_int(v), 0x112, 0xF, 0xF, true));
  v += __int_as_float(__builtin_amdgcn_update_dpp(0, __float_as_int(v), 0x114, 0xF, 0xF, true));
  v += __int_as_float(__builtin_amdgcn_update_dpp(0, __float_as_int(v), 0x118, 0xF, 0xF, true));
  v += __int_as_float(__builtin_amdgcn_update_dpp(0, __float_as_int(v), 0x142, 0xA, 0xF, true));
  v += __int_as_float(__builtin_amdgcn_update_dpp(0, __float_as_int(v), 0x143, 0xC, 0xF, true));
  return __int_as_float(__builtin_amdgcn_readlane(__float_as_int(v), 63));
}

// f32 triple quarter-dot (24 pk-fma), scalar results
__device__ __forceinline__ void dot3f(const float* base, const f32x2* w0, const f32x2* w1,
                                      const f32x2* w2, float& r0, float& r1, float& r2){
  f32x2 a={0.f,0.f}, b={0.f,0.f}, c={0.f,0.f};
  #pragma unroll
  for (int i=0;i<4;i++){
    F4 u; u.f4 = ((const float4*)base)[i];
    a = __builtin_elementwise_fma(w0[2*i], u.h[0], a);
    a = __builtin_elementwise_fma(w0[2*i+1], u.h[1], a);
    b = __builtin_elementwise_fma(w1[2*i], u.h[0], b);
    b = __builtin_elementwise_fma(w1[2*i+1], u.h[1], b);
    c = __builtin_elementwise_fma(w2[2*i], u.h[0], c);
    c = __builtin_elementwise_fma(w2[2*i+1], u.h[1], c);
  }
  r0 = a.x+a.y; r1 = b.x+b.y; r2 = c.x+c.y;
}

// f16 triple quarter-dot (24 v_dot2_f32_f16), f32 accumulators
__device__ __forceinline__ void dot3h(const f16x8* base, const f16x2* w0, const f16x2* w1,
                                      const f16x2* w2, float& r0, float& r1, float& r2){
  #pragma unroll
  for (int u2=0; u2<2; u2++){
    const f16x8 v = base[u2];
    #pragma unroll
    for (int i=0;i<4;i++){
      const f16x2 p = {v[2*i], v[2*i+1]};
      r0 = __builtin_amdgcn_fdot2(w0[4*u2+i], p, r0, false);
      r1 = __builtin_amdgcn_fdot2(w1[4*u2+i], p, r1, false);
      r2 = __builtin_amdgcn_fdot2(w2[4*u2+i], p, r2, false);
    }
  }
}

// 9 waves = 576 threads:
//   waves 0-3: layer-0 (16 rows/wave, lane = 4*row_local + quarter). ih f32 (x tile), hh f16.
//   waves 4-7: layer-1, ih+hh f16 (inputs are f16 h copies).
//   wave 8   : attention (f16 dot) + x stage (f32 pipeline, bursts at tt==0/32).
// Skew: iter it: L0@t=it, L1@t=it-2, attn@t=it-3. One raw barrier per iter.
// h kept dual: f32 master (update + pooling), f16 copy (dot inputs).
__global__ __launch_bounds__(576, 1)
void gru_attn_fused(const float* __restrict__ x,
                    const float* __restrict__ w_ih0, const float* __restrict__ w_hh0,
                    const float* __restrict__ b_ih0, const float* __restrict__ b_hh0,
                    const float* __restrict__ w_ih1, const float* __restrict__ w_hh1,
                    const float* __restrict__ b_ih1, const float* __restrict__ b_hh1,
                    const float* __restrict__ attn_w1, const float* __restrict__ attn_b1,
                    const float* __restrict__ attn_w2, const float* __restrict__ attn_b2,
                    const float* __restrict__ ln_g, const float* __restrict__ ln_b,
                    const float* __restrict__ head_w1, const float* __restrict__ head_b1,
                    const float* __restrict__ head_w2, const float* __restrict__ head_b2,
                    float* __restrict__ out)
{
  __shared__ float lds[LDSF];
  f16* lds16 = (f16*)&lds[H16F];
  const int tid  = threadIdx.x;
  const int b    = blockIdx.x;
  const int wid  = tid >> 6;
  const int lane = tid & 63;
  const float* xb = x + (size_t)b * 64 * TS;

  const bool isGate = (wid < 8);
  const int  l      = (wid >> 2) & 1;
  const int  row    = ((wid & 3) << 4) + (lane >> 2);  // 0..63
  const int  q16    = (lane & 3) << 4;                 // quarter col offset
  const int  q24    = (lane & 3) * 24;                 // f32 x-tile padded offset

  f32x2 WI[24];    // L0 only: w_ih0 quarter rows (f32)
  f16x2 WIH[24];   // L1 only: w_ih1 quarter rows (f16)
  f16x2 WHH[24];   // both:   w_hh quarter rows (f16)
  f16x2 WA[32];    // attn wave: attn_w1 row (f16)
  float4 SP[16];   // stage pipeline (wave 8)
  float brz_r=0.f, brz_z=0.f, bin_=0.f, bhn_=0.f, b1o=0.f, w2o=0.f, b2v=0.f;

  if (isGate) {
    const float* bih = l ? w_ih1 : w_ih0;
    const float* bhh = l ? w_hh1 : w_hh0;
    for (int g=0; g<3; g++){
      for (int i=0;i<8;i++){
        const f32x2 vih = *(const f32x2*)(bih + (g*64+row)*64 + q16 + 2*i);
        const f32x2 vhh = *(const f32x2*)(bhh + (g*64+row)*64 + q16 + 2*i);
        if (l==0) WI[8*g+i] = vih;
        else      WIH[8*g+i] = (f16x2){(f16)vih.x, (f16)vih.y};
        WHH[8*g+i] = (f16x2){(f16)vhh.x, (f16)vhh.y};
      }
    }
    if (l==0) {
      for (int k=0;k<24;k++) asm volatile("" : "+v"(WI[k]));
    } else {
      for (int k=0;k<24;k++) asm volatile("" : "+v"(WIH[k]));
    }
    for (int k=0;k<24;k++) asm volatile("" : "+v"(WHH[k]));
    const float* bi = l ? b_ih1 : b_ih0;
    const float* bh = l ? b_hh1 : b_hh0;
    brz_r = bi[row]      + bh[row];
    brz_z = bi[64+row]   + bh[64+row];
    bin_  = bi[128+row];
    bhn_  = bh[128+row];
  } else {
    for (int i=0;i<32;i++){
      const f32x2 v = *(const f32x2*)(attn_w1 + lane*64 + 2*i);
      WA[i] = (f16x2){(f16)v.x, (f16)v.y};
    }
    for (int k=0;k<32;k++) asm volatile("" : "+v"(WA[k]));
    b1o = attn_b1[lane]; w2o = attn_w2[lane]; b2v = attn_b2[0];
  }

  // prologue: zero h (f32 + f16), stage x tile 0 (swizzled f32 transpose)
  if (tid < 256) lds[HF32 + tid] = 0.f;
  if (tid < 128) ((uint32_t*)lds16)[tid] = 0u;
  if (tid < 256) {
    const int c = tid >> 2, t0 = (tid & 3) << 4;
    const int sc = SWZ(c);
    #pragma unroll
    for (int m=0;m<4;m++){
      float4 v = *(const float4*)(xb + c*TS + t0 + 4*m);
      lds[XT0 + (t0+4*m+0)*RSTR + sc] = v.x;
      lds[XT0 + (t0+4*m+1)*RSTR + sc] = v.y;
      lds[XT0 + (t0+4*m+2)*RSTR + sc] = v.z;
      lds[XT0 + (t0+4*m+3)*RSTR + sc] = v.w;
    }
  }
  __syncthreads();

  float stR=0.f, stZ=0.f, stN=0.f;         // ih-dot stash (gate waves)
  float am = -1e30f, aZ = 0.f, aP = 0.f;   // online softmax (wave 8)

  if (isGate && l==0) dot3f(&lds[XT0 + q24], WI, WI+8, WI+16, stR, stZ, stN);

  #pragma unroll 1
  for (int it = 0; it < TS + 3; ++it) {
    const int rb   = it & 1;
    const int wb   = rb ^ 1;
    const int tile = it >> 6;
    const int xsel = tile & 1;
    const int tt   = it & 63;

    if (isGate) {
      const bool act = (l==0) ? (it < TS) : (it >= 2 && it <= TS+1);
      if (act) {
        const f16x8* hv = (const f16x8*)(lds16 + ((l*2+rb)<<6) + q16);
        float cr=0.f, cz=0.f, cn=0.f;
        dot3h(hv, WHH, WHH+8, WHH+16, cr, cz, cn);
        const float sr = qadd2(stR + cr);
        const float sz = qadd2(stZ + cz);
        const float xn = qadd2(stN);
        const float hn = qadd2(cn);
        const float r  = sigmoidf_(sr + brz_r);
        const float z  = sigmoidf_(sz + brz_z);
        const float n  = tanhf_((xn + bin_) + r*(hn + bhn_));
        const float hold = lds[HF32 + ((l*2+rb)<<6) + row];
        const float hnew = n + z*(hold - n);
        if ((lane & 3) == 0) {
          lds[HF32 + ((l*2+wb)<<6) + row] = hnew;
          lds16[((l*2+wb)<<6) + row] = (f16)hnew;
        }
      }
      if (l==0) {
        if (it+1 < TS) {
          const int ix = it+1;
          const float* xv = &lds[(((ix>>6)&1)?XT1:XT0) + (ix&63)*RSTR + q24];
          dot3f(xv, WI, WI+8, WI+16, stR, stZ, stN);
        }
      } else {
        if (it >= 1 && it <= TS) {
          const f16x8* gv = (const f16x8*)(lds16 + (rb<<6) + q16);  // h0[rb]
          float a0=0.f, a1=0.f, a2=0.f;
          dot3h(gv, WIH, WIH+8, WIH+16, a0, a1, a2);
          stR=a0; stZ=a1; stN=a2;
        }
      }
    } else { // wave 8: attention + stage
      if (it >= 3 && it <= TS+2) {
        const f16x8* hv = (const f16x8*)(lds16 + ((2+rb)<<6));
        float p0=0.f, p1=0.f, p2=0.f, p3=0.f;
        #pragma unroll
        for (int u2=0;u2<8;u2++){
          const f16x8 v = hv[u2];
          float* acc = (u2<2)? &p0 : (u2<4)? &p1 : (u2<6)? &p2 : &p3;
          #pragma unroll
          for (int i=0;i<4;i++){
            const f16x2 pp = {v[2*i], v[2*i+1]};
            *acc = __builtin_amdgcn_fdot2(WA[4*u2+i], pp, *acc, false);
          }
        }
        const float a  = tanhf_(((p0+p1)+(p2+p3)) + b1o);
        const float s  = wsum64(w2o * a) + b2v;
        const float h1v = lds[HF32 + ((2+rb)<<6) + lane];
        const float mn = fmaxf(am, s);
        const float sc = __expf(am - mn);
        const float p  = __expf(s - mn);
        aZ = aZ*sc + p;
        aP = aP*sc + p*h1v;
        am = mn;
      }
      if (tile <= 30) {
        if (tt == 0) {
          const float* src = xb + (lane>>4)*TS + (tile+1)*64 + ((lane&15)<<2);
          #pragma unroll
          for (int k=0;k<16;k++) SP[k] = *(const float4*)(src + (size_t)k*4*TS);
        } else if (tt == 32) {
          float* dst = &lds[xsel ? XT0 : XT1];
          const int c0 = lane >> 4, t4 = (lane & 15) << 2;
          #pragma unroll
          for (int k=0;k<16;k++){
            const int oc = (k>>2)*24 + 4*(k&3) + c0;   // SWZ(4k + c0)
            dst[(t4+0)*RSTR + oc] = SP[k].x;
            dst[(t4+1)*RSTR + oc] = SP[k].y;
            dst[(t4+2)*RSTR + oc] = SP[k].z;
            dst[(t4+3)*RSTR + oc] = SP[k].w;
          }
        }
      }
    }
    BAR();
  }

  // ---------------- epilogue ----------------
  if (wid == 8) {
    const float pooled = aP / aZ;
    float mu = pooled;
    #pragma unroll
    for (int m=1;m<64;m<<=1) mu += __shfl_xor(mu, m, 64);
    mu *= (1.0f/64.0f);
    const float d = pooled - mu;
    float var = d*d;
    #pragma unroll
    for (int m=1;m<64;m<<=1) var += __shfl_xor(var, m, 64);
    var *= (1.0f/64.0f);
    const float y = d * rsqrtf(var + 1e-5f) * ln_g[lane] + ln_b[lane];
    lds[SCRO + lane] = y;
  }
  __syncthreads();
  if (tid < 32) {
    const float* hw = head_w1 + tid*64;
    float acc = head_b1[tid];
    #pragma unroll
    for (int k=0;k<16;k++){
      const float4 w4 = ((const float4*)hw)[k];
      acc += w4.x*lds[SCRO+4*k+0] + w4.y*lds[SCRO+4*k+1]
           + w4.z*lds[SCRO+4*k+2] + w4.w*lds[SCRO+4*k+3];
    }
    const float u = 0.5f*acc*(1.0f + erff(acc*0.70710678118654752f)); // exact GELU
    lds[SCRO + 64 + tid] = u;
  }
  __syncthreads();
  if (tid < 8) {
    const float* hw = head_w2 + tid*32;
    float acc = head_b2[tid];
    #pragma unroll
    for (int k=0;k<8;k++){
      const float4 w4 = ((const float4*)hw)[k];
      acc += w4.x*lds[SCRO+64+4*k+0] + w4.y*lds[SCRO+64+4*k+1]
           + w4.z*lds[SCRO+64+4*k+2] + w4.w*lds[SCRO+64+4*k+3];
    }
    out[b*8 + tid] = acc;
  }
}

extern "C" void kernel_launch(void* const* d_in, const int* in_sizes, int n_in,
                              void* d_out, int out_size, void* d_ws, size_t ws_size,
                              hipStream_t stream) {
  (void)in_sizes; (void)n_in; (void)d_ws; (void)ws_size; (void)out_size;
  const float* x       = (const float*)d_in[0];
  const float* w_ih0   = (const float*)d_in[1];
  const float* w_hh0   = (const float*)d_in[2];
  const float* b_ih0   = (const float*)d_in[3];
  const float* b_hh0   = (const float*)d_in[4];
  const float* w_ih1   = (const float*)d_in[5];
  const float* w_hh1   = (const float*)d_in[6];
  const float* b_ih1   = (const float*)d_in[7];
  const float* b_hh1   = (const float*)d_in[8];
  const float* attn_w1 = (const float*)d_in[9];
  const float* attn_b1 = (const float*)d_in[10];
  const float* attn_w2 = (const float*)d_in[11];
  const float* attn_b2 = (const float*)d_in[12];
  const float* ln_g    = (const float*)d_in[13];
  const float* ln_b    = (const float*)d_in[14];
  const float* head_w1 = (const float*)d_in[15];
  const float* head_b1 = (const float*)d_in[16];
  const float* head_w2 = (const float*)d_in[17];
  const float* head_b2 = (const float*)d_in[18];
  hipLaunchKernelGGL(gru_attn_fused, dim3(256), dim3(576), 0, stream,
                     x, w_ih0, w_hh0, b_ih0, b_hh0, w_ih1, w_hh1, b_ih1, b_hh1,
                     attn_w1, attn_b1, attn_w2, attn_b2, ln_g, ln_b,
                     head_w1, head_b1, head_w2, head_b2, (float*)d_out);
}

// Round 9
// 1354.348 us; speedup vs baseline: 4.1723x; 4.1723x over previous
//
#include <hip/hip_runtime.h>
#include <math.h>

#define TS 2048

typedef float f32x2 __attribute__((ext_vector_type(2)));
typedef _Float16 f16;
typedef _Float16 f16x2 __attribute__((ext_vector_type(2)));
typedef _Float16 f16x8 __attribute__((ext_vector_type(8)));

// LDS float-index offsets. x tiles are f16 [64 t][64 c] (8KB each): quarter
// reads at 32B offsets -> 4 disjoint bank groups, conflict-free, no padding.
#define XT1F   4096   // f16 element index of tile 1 (tile 0 at 0)
#define HF32   4096   // float idx: h f32 [2 layer][2 parity][64]
#define H16F   4352   // float idx: h f16 [2 layer][2 parity][64] (256 f16)
#define SCRO   4480
#define LDSF   4608

// Raw barrier: LDS-ordering only, NO vmcnt drain (stage prefetch stays in flight)
#define BAR() do { asm volatile("s_waitcnt lgkmcnt(0)" ::: "memory"); __builtin_amdgcn_s_barrier(); } while(0)

union H8 { f16x8 v8; f16x2 v2[4]; };

__device__ __forceinline__ float sigmoidf_(float v){ return __builtin_amdgcn_rcpf(1.0f+__expf(-v)); }
__device__ __forceinline__ float tanhf_(float v){
  v = fminf(15.0f, fmaxf(-15.0f, v));
  const float e = __expf(2.0f*v);
  return (e-1.0f)*__builtin_amdgcn_rcpf(e+1.0f);
}
__device__ __forceinline__ float qadd2(float v){
  float a = v + __int_as_float(__builtin_amdgcn_update_dpp(0, __float_as_int(v), 0xB1, 0xF, 0xF, true));
  return a + __int_as_float(__builtin_amdgcn_update_dpp(0, __float_as_int(a), 0x4E, 0xF, 0xF, true));
}
__device__ __forceinline__ float wsum64(float v){
  v += __int_as_float(__builtin_amdgcn_update_dpp(0, __float_as_int(v), 0x111, 0xF, 0xF, true));
  v += __int_as_float(__builtin_amdgcn_update_dpp(0, __float_as_int(v), 0x112, 0xF, 0xF, true));
  v += __int_as_float(__builtin_amdgcn_update_dpp(0, __float_as_int(v), 0x114, 0xF, 0xF, true));
  v += __int_as_float(__builtin_amdgcn_update_dpp(0, __float_as_int(v), 0x118, 0xF, 0xF, true));
  v += __int_as_float(__builtin_amdgcn_update_dpp(0, __float_as_int(v), 0x142, 0xA, 0xF, true));
  v += __int_as_float(__builtin_amdgcn_update_dpp(0, __float_as_int(v), 0x143, 0xC, 0xF, true));
  return __int_as_float(__builtin_amdgcn_readlane(__float_as_int(v), 63));
}

// 16-f16 triple dot: 24 v_dot2_f32_f16, f32 accumulation. Inputs via H8 union
// (f16x2 lanes of the packed b128 loads -> zero marshalling movs).
__device__ __forceinline__ void dot3h(const f16* base, const f16x2* w0, const f16x2* w1,
                                      const f16x2* w2, float& r0, float& r1, float& r2){
  #pragma unroll
  for (int u=0; u<2; u++){
    H8 x; x.v8 = *(const f16x8*)(base + 8*u);
    #pragma unroll
    for (int i=0;i<4;i++){
      r0 = __builtin_amdgcn_fdot2(w0[4*u+i], x.v2[i], r0, false);
      r1 = __builtin_amdgcn_fdot2(w1[4*u+i], x.v2[i], r1, false);
      r2 = __builtin_amdgcn_fdot2(w2[4*u+i], x.v2[i], r2, false);
    }
  }
}

// One timestep body; RB is a compile-time parity constant (unroll-by-2).
#define STEP(IT, RB) do {                                                            \
    const int it_   = (IT);                                                          \
    const int tile_ = it_ >> 6;                                                      \
    const int xsel_ = tile_ & 1;                                                     \
    const int tt_   = it_ & 63;                                                      \
    if (isGate) {                                                                    \
      __builtin_amdgcn_s_setprio(1);                                                 \
      const bool act = (l==0) ? (it_ < TS) : (it_ >= 2 && it_ <= TS+1);              \
      if (act) {                                                                     \
        const f16* hv = lds16h + hb16 + (RB)*64 + q16;                               \
        float cr=0.f, cz=0.f, cn=0.f;                                                \
        dot3h(hv, W16+24, W16+32, W16+40, cr, cz, cn);                               \
        const float sr = qadd2(stR + cr);                                            \
        const float sz = qadd2(stZ + cz);                                            \
        const float xn = qadd2(stN);                                                 \
        const float hn = qadd2(cn);                                                  \
        const float r  = sigmoidf_(sr + brz_r);                                      \
        const float z  = sigmoidf_(sz + brz_z);                                      \
        const float n  = tanhf_((xn + bin_) + r*(hn + bhn_));                        \
        const float hold = lds[HF32 + hb16 + (RB)*64 + row];                         \
        const float hnew = n + z*(hold - n);                                         \
        if ((lane & 3) == 0) {                                                       \
          lds[HF32 + hb16 + ((RB)^1)*64 + row] = hnew;                               \
          lds16h[hb16 + ((RB)^1)*64 + row] = (f16)hnew;                              \
        }                                                                            \
      }                                                                              \
      if (l==0) {                                                                    \
        const int ix = it_ + 1;                                                      \
        if (ix < TS) {                                                               \
          const f16* xv = ldsxh + ((ix>>6)&1)*XT1F + (ix&63)*64 + q16;               \
          float a0=0.f, a1=0.f, a2=0.f;                                              \
          dot3h(xv, W16+0, W16+8, W16+16, a0, a1, a2);                               \
          stR=a0; stZ=a1; stN=a2;                                                    \
        }                                                                            \
      } else {                                                                       \
        if (it_ >= 1 && it_ <= TS) {                                                 \
          const f16* gv = lds16h + (RB)*64 + q16;  /* h0[RB] */                      \
          float a0=0.f, a1=0.f, a2=0.f;                                              \
          dot3h(gv, W16+0, W16+8, W16+16, a0, a1, a2);                               \
          stR=a0; stZ=a1; stN=a2;                                                    \
        }                                                                            \
      }                                                                              \
      __builtin_amdgcn_s_setprio(0);                                                 \
    } else if (isAttn) {                                                             \
      if (it_ >= 3 && it_ <= TS+2) {                                                 \
        const f16* hb = lds16h + 128 + (RB)*64;                                      \
        float p0=0.f, p1=0.f, p2=0.f, p3=0.f;                                        \
        { H8 x; x.v8 = *(const f16x8*)(hb+ 0);                                       \
          p0=__builtin_amdgcn_fdot2(W16[ 0],x.v2[0],p0,false);                       \
          p0=__builtin_amdgcn_fdot2(W16[ 1],x.v2[1],p0,false);                       \
          p0=__builtin_amdgcn_fdot2(W16[ 2],x.v2[2],p0,false);                       \
          p0=__builtin_amdgcn_fdot2(W16[ 3],x.v2[3],p0,false);                       \
          x.v8 = *(const f16x8*)(hb+ 8);                                             \
          p0=__builtin_amdgcn_fdot2(W16[ 4],x.v2[0],p0,false);                       \
          p0=__builtin_amdgcn_fdot2(W16[ 5],x.v2[1],p0,false);                       \
          p0=__builtin_amdgcn_fdot2(W16[ 6],x.v2[2],p0,false);                       \
          p0=__builtin_amdgcn_fdot2(W16[ 7],x.v2[3],p0,false); }                     \
        { H8 x; x.v8 = *(const f16x8*)(hb+16);                                       \
          p1=__builtin_amdgcn_fdot2(W16[ 8],x.v2[0],p1,false);                       \
          p1=__builtin_amdgcn_fdot2(W16[ 9],x.v2[1],p1,false);                       \
          p1=__builtin_amdgcn_fdot2(W16[10],x.v2[2],p1,false);                       \
          p1=__builtin_amdgcn_fdot2(W16[11],x.v2[3],p1,false);                       \
          x.v8 = *(const f16x8*)(hb+24);                                             \
          p1=__builtin_amdgcn_fdot2(W16[12],x.v2[0],p1,false);                       \
          p1=__builtin_amdgcn_fdot2(W16[13],x.v2[1],p1,false);                       \
          p1=__builtin_amdgcn_fdot2(W16[14],x.v2[2],p1,false);                       \
          p1=__builtin_amdgcn_fdot2(W16[15],x.v2[3],p1,false); }                     \
        { H8 x; x.v8 = *(const f16x8*)(hb+32);                                       \
          p2=__builtin_amdgcn_fdot2(W16[16],x.v2[0],p2,false);                       \
          p2=__builtin_amdgcn_fdot2(W16[17],x.v2[1],p2,false);                       \
          p2=__builtin_amdgcn_fdot2(W16[18],x.v2[2],p2,false);                       \
          p2=__builtin_amdgcn_fdot2(W16[19],x.v2[3],p2,false);                       \
          x.v8 = *(const f16x8*)(hb+40);                                             \
          p2=__builtin_amdgcn_fdot2(W16[20],x.v2[0],p2,false);                       \
          p2=__builtin_amdgcn_fdot2(W16[21],x.v2[1],p2,false);                       \
          p2=__builtin_amdgcn_fdot2(W16[22],x.v2[2],p2,false);                       \
          p2=__builtin_amdgcn_fdot2(W16[23],x.v2[3],p2,false); }                     \
        { H8 x; x.v8 = *(const f16x8*)(hb+48);                                       \
          p3=__builtin_amdgcn_fdot2(W16[24],x.v2[0],p3,false);                       \
          p3=__builtin_amdgcn_fdot2(W16[25],x.v2[1],p3,false);                       \
          p3=__builtin_amdgcn_fdot2(W16[26],x.v2[2],p3,false);                       \
          p3=__builtin_amdgcn_fdot2(W16[27],x.v2[3],p3,false);                       \
          x.v8 = *(const f16x8*)(hb+56);                                             \
          p3=__builtin_amdgcn_fdot2(W16[28],x.v2[0],p3,false);                       \
          p3=__builtin_amdgcn_fdot2(W16[29],x.v2[1],p3,false);                       \
          p3=__builtin_amdgcn_fdot2(W16[30],x.v2[2],p3,false);                       \
          p3=__builtin_amdgcn_fdot2(W16[31],x.v2[3],p3,false); }                     \
        const float a  = tanhf_(((p0+p1)+(p2+p3)) + b1o);                            \
        const float s  = wsum64(w2o * a) + b2v;                                      \
        const float h1v = lds[HF32 + 128 + (RB)*64 + lane];                          \
        const float mn = fmaxf(am, s);                                               \
        const float sc = __expf(am - mn);                                            \
        const float p  = __expf(s - mn);                                             \
        aZ = aZ*sc + p;                                                              \
        aP = aP*sc + p*h1v;                                                          \
        am = mn;                                                                     \
      }                                                                              \
    } else { /* stage wave */                                                        \
      if (tile_ <= 30) {                                                             \
        if (tt_ == 0) {                                                              \
          const float* src = xb + (lane>>4)*TS + (tile_+1)*64 + ((lane&15)<<2);      \
          _Pragma("unroll")                                                          \
          for (int k=0;k<16;k++) SP[k] = *(const float4*)(src + (size_t)k*4*TS);     \
        } else if (tt_ == 32) {                                                      \
          f16* dsth = ldsxh + (xsel_ ? 0 : XT1F);                                    \
          const int c0 = lane >> 4, t4 = (lane & 15) << 2;                           \
          _Pragma("unroll")                                                          \
          for (int k=0;k<16;k++){                                                    \
            const int cc = 4*k + c0;                                                 \
            dsth[(t4+0)*64 + cc] = (f16)SP[k].x;                                     \
            dsth[(t4+1)*64 + cc] = (f16)SP[k].y;                                     \
            dsth[(t4+2)*64 + cc] = (f16)SP[k].z;                                     \
            dsth[(t4+3)*64 + cc] = (f16)SP[k].w;                                     \
          }                                                                          \
        }                                                                            \
      }                                                                              \
    }                                                                                \
    BAR();                                                                           \
  } while(0)

// 10 waves = 640 threads: 0-3 L0, 4-7 L1 (16 rows/wave, lane=4*row+quarter),
// 8 attn, 9 stage. Skew: L0@t=it, L1@t=it-2, attn@t=it-3. 1 raw barrier/step.
__global__ __launch_bounds__(640, 1)
void gru_attn_fused(const float* __restrict__ x,
                    const float* __restrict__ w_ih0, const float* __restrict__ w_hh0,
                    const float* __restrict__ b_ih0, const float* __restrict__ b_hh0,
                    const float* __restrict__ w_ih1, const float* __restrict__ w_hh1,
                    const float* __restrict__ b_ih1, const float* __restrict__ b_hh1,
                    const float* __restrict__ attn_w1, const float* __restrict__ attn_b1,
                    const float* __restrict__ attn_w2, const float* __restrict__ attn_b2,
                    const float* __restrict__ ln_g, const float* __restrict__ ln_b,
                    const float* __restrict__ head_w1, const float* __restrict__ head_b1,
                    const float* __restrict__ head_w2, const float* __restrict__ head_b2,
                    float* __restrict__ out)
{
  __shared__ float lds[LDSF];
  f16* ldsxh  = (f16*)&lds[0];      // x tiles, f16
  f16* lds16h = (f16*)&lds[H16F];   // h f16 [l][parity][64]
  const int tid  = threadIdx.x;
  const int b    = blockIdx.x;
  const int wid  = tid >> 6;
  const int lane = tid & 63;
  const float* xb = x + (size_t)b * 64 * TS;

  const bool isGate = (wid < 8);
  const bool isAttn = (wid == 8);
  const int  l      = (wid >> 2) & 1;
  const int  row    = ((wid & 3) << 4) + (lane >> 2);  // 0..63
  const int  q16    = (lane & 3) << 4;                 // quarter col offset (elems)
  const int  hb16   = l * 128;                         // h base (elems/floats)

  // Single role-shared register array (f16x2 = 1 VGPR each):
  //   gate: [0..23] = ih r/z/n quarter rows, [24..47] = hh r/z/n
  //   attn: [0..31] = attn_w1 row
  f16x2 W16[48];
  float4 SP[16];   // stage-wave prefetch pipeline only
  float brz_r=0.f, brz_z=0.f, bin_=0.f, bhn_=0.f, b1o=0.f, w2o=0.f, b2v=0.f;

  if (isGate) {
    const float* bih = l ? w_ih1 : w_ih0;
    const float* bhh = l ? w_hh1 : w_hh0;
    for (int g=0; g<3; g++){
      for (int i=0;i<8;i++){
        const f32x2 vih = *(const f32x2*)(bih + (g*64+row)*64 + q16 + 2*i);
        const f32x2 vhh = *(const f32x2*)(bhh + (g*64+row)*64 + q16 + 2*i);
        W16[g*8+i]    = (f16x2){(f16)vih.x, (f16)vih.y};
        W16[24+g*8+i] = (f16x2){(f16)vhh.x, (f16)vhh.y};
      }
    }
    for (int k=0;k<48;k++) asm volatile("" : "+v"(W16[k]));
    const float* bi = l ? b_ih1 : b_ih0;
    const float* bh = l ? b_hh1 : b_hh0;
    brz_r = bi[row]      + bh[row];
    brz_z = bi[64+row]   + bh[64+row];
    bin_  = bi[128+row];
    bhn_  = bh[128+row];
  } else if (isAttn) {
    for (int i=0;i<32;i++){
      const f32x2 v = *(const f32x2*)(attn_w1 + lane*64 + 2*i);
      W16[i] = (f16x2){(f16)v.x, (f16)v.y};
    }
    for (int k=0;k<32;k++) asm volatile("" : "+v"(W16[k]));
    b1o = attn_b1[lane]; w2o = attn_w2[lane]; b2v = attn_b2[0];
  }

  // prologue: zero h (f32 + f16), stage x tile 0 (f16 transpose)
  if (tid < 256) lds[HF32 + tid] = 0.f;
  if (tid >= 256 && tid < 384) ((uint32_t*)lds16h)[tid-256] = 0u;
  if (tid < 256) {
    const int c = tid >> 2, t0 = (tid & 3) << 4;
    #pragma unroll
    for (int m4=0;m4<4;m4++){
      float4 v = *(const float4*)(xb + c*TS + t0 + 4*m4);
      ldsxh[(t0+4*m4+0)*64 + c] = (f16)v.x;
      ldsxh[(t0+4*m4+1)*64 + c] = (f16)v.y;
      ldsxh[(t0+4*m4+2)*64 + c] = (f16)v.z;
      ldsxh[(t0+4*m4+3)*64 + c] = (f16)v.w;
    }
  }
  __syncthreads();

  float stR=0.f, stZ=0.f, stN=0.f;         // ih-dot stash (gate waves)
  float am = -1e30f, aZ = 0.f, aP = 0.f;   // online softmax (wave 8)

  if (isGate && l==0) {
    float a0=0.f, a1=0.f, a2=0.f;
    dot3h(ldsxh + q16, W16+0, W16+8, W16+16, a0, a1, a2);
    stR=a0; stZ=a1; stN=a2;
  }

  #pragma unroll 1
  for (int itb = 0; itb < TS + 4; itb += 2) {
    STEP(itb,   0);
    STEP(itb+1, 1);
  }

  // ---------------- epilogue ----------------
  if (isAttn) {
    const float pooled = aP / aZ;
    float mu = pooled;
    #pragma unroll
    for (int m=1;m<64;m<<=1) mu += __shfl_xor(mu, m, 64);
    mu *= (1.0f/64.0f);
    const float d = pooled - mu;
    float var = d*d;
    #pragma unroll
    for (int m=1;m<64;m<<=1) var += __shfl_xor(var, m, 64);
    var *= (1.0f/64.0f);
    const float y = d * rsqrtf(var + 1e-5f) * ln_g[lane] + ln_b[lane];
    lds[SCRO + lane] = y;
  }
  __syncthreads();
  if (tid < 32) {
    const float* hw = head_w1 + tid*64;
    float acc = head_b1[tid];
    #pragma unroll
    for (int k=0;k<16;k++){
      const float4 w4 = ((const float4*)hw)[k];
      acc += w4.x*lds[SCRO+4*k+0] + w4.y*lds[SCRO+4*k+1]
           + w4.z*lds[SCRO+4*k+2] + w4.w*lds[SCRO+4*k+3];
    }
    const float u = 0.5f*acc*(1.0f + erff(acc*0.70710678118654752f)); // exact GELU
    lds[SCRO + 64 + tid] = u;
  }
  __syncthreads();
  if (tid < 8) {
    const float* hw = head_w2 + tid*32;
    float acc = head_b2[tid];
    #pragma unroll
    for (int k=0;k<8;k++){
      const float4 w4 = ((const float4*)hw)[k];
      acc += w4.x*lds[SCRO+64+4*k+0] + w4.y*lds[SCRO+64+4*k+1]
           + w4.z*lds[SCRO+64+4*k+2] + w4.w*lds[SCRO+64+4*k+3];
    }
    out[b*8 + tid] = acc;
  }
}

extern "C" void kernel_launch(void* const* d_in, const int* in_sizes, int n_in,
                              void* d_out, int out_size, void* d_ws, size_t ws_size,
                              hipStream_t stream) {
  (void)in_sizes; (void)n_in; (void)d_ws; (void)ws_size; (void)out_size;
  const float* x       = (const float*)d_in[0];
  const float* w_ih0   = (const float*)d_in[1];
  const float* w_hh0   = (const float*)d_in[2];
  const float* b_ih0   = (const float*)d_in[3];
  const float* b_hh0   = (const float*)d_in[4];
  const float* w_ih1   = (const float*)d_in[5];
  const float* w_hh1   = (const float*)d_in[6];
  const float* b_ih1   = (const float*)d_in[7];
  const float* b_hh1   = (const float*)d_in[8];
  const float* attn_w1 = (const float*)d_in[9];
  const float* attn_b1 = (const float*)d_in[10];
  const float* attn_w2 = (const float*)d_in[11];
  const float* attn_b2 = (const float*)d_in[12];
  const float* ln_g    = (const float*)d_in[13];
  const float* ln_b    = (const float*)d_in[14];
  const float* head_w1 = (const float*)d_in[15];
  const float* head_b1 = (const float*)d_in[16];
  const float* head_w2 = (const float*)d_in[17];
  const float* head_b2 = (const float*)d_in[18];
  hipLaunchKernelGGL(gru_attn_fused, dim3(256), dim3(640), 0, stream,
                     x, w_ih0, w_hh0, b_ih0, b_hh0, w_ih1, w_hh1, b_ih1, b_hh1,
                     attn_w1, attn_b1, attn_w2, attn_b2, ln_g, ln_b,
                     head_w1, head_b1, head_w2, head_b2, (float*)d_out);
}

// Round 10
// 1232.799 us; speedup vs baseline: 4.5837x; 1.0986x over previous
//
#include <hip/hip_runtime.h>
#include <math.h>

#define TS 2048
#define XROW 72      // padded f16 row stride for x tiles (144B, 16B-aligned)
#define XT1F 4608    // f16 idx of x tile 1 (tile 0 at 0); each tile 64*72 f16
#define H1F  4736    // float idx: h1 f32 [2 parity][64] (attn pooling only)
#define SCRO 4864    // float idx: epilogue scratch
#define LDSF 4960

typedef float f32x2 __attribute__((ext_vector_type(2)));
typedef _Float16 f16;
typedef _Float16 f16x2 __attribute__((ext_vector_type(2)));
typedef _Float16 f16x8 __attribute__((ext_vector_type(8)));

// Raw barrier: LDS-ordering only, NO vmcnt drain (stage prefetch stays in flight)
#define BAR() do { asm volatile("s_waitcnt lgkmcnt(0)" ::: "memory"); __builtin_amdgcn_s_barrier(); } while(0)

union H8 { f16x8 v8; f16x2 v2[4]; };

__device__ __forceinline__ float sigmoidf_(float v){ return __builtin_amdgcn_rcpf(1.0f+__expf(-v)); }
__device__ __forceinline__ float tanhf_(float v){
  v = fminf(15.0f, fmaxf(-15.0f, v));
  const float e = __expf(2.0f*v);
  return (e-1.0f)*__builtin_amdgcn_rcpf(e+1.0f);
}
__device__ __forceinline__ float qadd2(float v){
  float a = v + __int_as_float(__builtin_amdgcn_update_dpp(0, __float_as_int(v), 0xB1, 0xF, 0xF, true));
  return a + __int_as_float(__builtin_amdgcn_update_dpp(0, __float_as_int(a), 0x4E, 0xF, 0xF, true));
}
__device__ __forceinline__ float wsum64(float v){
  v += __int_as_float(__builtin_amdgcn_update_dpp(0, __float_as_int(v), 0x111, 0xF, 0xF, true));
  v += __int_as_float(__builtin_amdgcn_update_dpp(0, __float_as_int(v), 0x112, 0xF, 0xF, true));
  v += __int_as_float(__builtin_amdgcn_update_dpp(0, __float_as_int(v), 0x114, 0xF, 0xF, true));
  v += __int_as_float(__builtin_amdgcn_update_dpp(0, __float_as_int(v), 0x118, 0xF, 0xF, true));
  v += __int_as_float(__builtin_amdgcn_update_dpp(0, __float_as_int(v), 0x142, 0xA, 0xF, true));
  v += __int_as_float(__builtin_amdgcn_update_dpp(0, __float_as_int(v), 0x143, 0xC, 0xF, true));
  return __int_as_float(__builtin_amdgcn_readlane(__float_as_int(v), 63));
}

// 16-f16 triple dot: 24 v_dot2_f32_f16, f32 accumulation (r* must be zero-inited)
__device__ __forceinline__ void dot3h(const f16* base, const f16x2* w0, const f16x2* w1,
                                      const f16x2* w2, float& r0, float& r1, float& r2){
  #pragma unroll
  for (int u=0; u<2; u++){
    H8 x; x.v8 = *(const f16x8*)(base + 8*u);
    #pragma unroll
    for (int i=0;i<4;i++){
      r0 = __builtin_amdgcn_fdot2(w0[4*u+i], x.v2[i], r0, false);
      r1 = __builtin_amdgcn_fdot2(w1[4*u+i], x.v2[i], r1, false);
      r2 = __builtin_amdgcn_fdot2(w2[4*u+i], x.v2[i], r2, false);
    }
  }
}

// 6 waves = 384 threads:
//   waves 0-1: layer 0 halves; waves 2-3: layer 1 halves.
//     gate thread: rows {rl, rl+32}, rl = (wid&1)*16 + (lane>>2); cols q*16 (q=lane&3).
//     96 f16x2 weights; quad DPP reduce; h master register-carried (hold).
//   wave 4: attention (lane = row, full 64-dot). wave 5: x stage.
// Skew: L0@t=it, L1@t=it-2, attn@t=it-3. ONE raw barrier/step; h f16 parity dbuf.
__global__ __launch_bounds__(384, 1)
void gru_attn_fused(const float* __restrict__ x,
                    const float* __restrict__ w_ih0, const float* __restrict__ w_hh0,
                    const float* __restrict__ b_ih0, const float* __restrict__ b_hh0,
                    const float* __restrict__ w_ih1, const float* __restrict__ w_hh1,
                    const float* __restrict__ b_ih1, const float* __restrict__ b_hh1,
                    const float* __restrict__ attn_w1, const float* __restrict__ attn_b1,
                    const float* __restrict__ attn_w2, const float* __restrict__ attn_b2,
                    const float* __restrict__ ln_g, const float* __restrict__ ln_b,
                    const float* __restrict__ head_w1, const float* __restrict__ head_b1,
                    const float* __restrict__ head_w2, const float* __restrict__ head_b2,
                    float* __restrict__ out)
{
  __shared__ float lds[LDSF];
  f16* ldsxh  = (f16*)&lds[0];      // x tiles (f16, XROW stride)
  f16* lds16h = (f16*)&lds[4608];   // h f16 [layer][parity][64]
  const int tid  = threadIdx.x;
  const int b    = blockIdx.x;
  const int wid  = tid >> 6;
  const int lane = tid & 63;
  const float* xb = x + (size_t)b * 64 * TS;

  const bool isGate = (wid < 4);
  const bool isAttn = (wid == 4);
  const int  l      = wid >> 1;                       // gate layer (0/1)
  const int  row0   = ((wid & 1) << 4) + (lane >> 2); // rows {row0, row0+32}
  const int  row1   = row0 + 32;
  const int  q16    = (lane & 3) << 4;                // quarter col offset
  const int  hb     = l << 7;                         // h f16 base (layer*128)

  // gate: Wih[0..23]=row0 r/z/n quarters, [24..47]=row1; Whh same for hh.
  // attn: Wih[0..31] = attn_w1 row.
  f16x2 Wih[48], Whh[48];
  float4 SP[16];   // stage prefetch pipeline
  float bR0=0,bZ0=0,bI0=0,bH0=0,bR1=0,bZ1=0,bI1=0,bH1=0;
  float b1o=0, w2o=0, b2v=0;

  if (isGate) {
    const float* bih = l ? w_ih1 : w_ih0;
    const float* bhh = l ? w_hh1 : w_hh0;
    for (int r2=0;r2<2;r2++){
      const int row = r2 ? row1 : row0;
      for (int g=0; g<3; g++){
        for (int i=0;i<8;i++){
          const f32x2 vi = *(const f32x2*)(bih + (g*64+row)*64 + q16 + 2*i);
          const f32x2 vh = *(const f32x2*)(bhh + (g*64+row)*64 + q16 + 2*i);
          Wih[r2*24+g*8+i] = (f16x2){(f16)vi.x, (f16)vi.y};
          Whh[r2*24+g*8+i] = (f16x2){(f16)vh.x, (f16)vh.y};
        }
      }
    }
    for (int k=0;k<48;k++) asm volatile("" : "+v"(Wih[k]));
    for (int k=0;k<48;k++) asm volatile("" : "+v"(Whh[k]));
    const float* bi = l ? b_ih1 : b_ih0;
    const float* bh = l ? b_hh1 : b_hh0;
    bR0 = bi[row0] + bh[row0];      bR1 = bi[row1] + bh[row1];
    bZ0 = bi[64+row0] + bh[64+row0]; bZ1 = bi[64+row1] + bh[64+row1];
    bI0 = bi[128+row0];             bI1 = bi[128+row1];
    bH0 = bh[128+row0];             bH1 = bh[128+row1];
  } else if (isAttn) {
    for (int i=0;i<32;i++){
      const f32x2 v = *(const f32x2*)(attn_w1 + lane*64 + 2*i);
      Wih[i] = (f16x2){(f16)v.x, (f16)v.y};
    }
    for (int k=0;k<32;k++) asm volatile("" : "+v"(Wih[k]));
    b1o = attn_b1[lane]; w2o = attn_w2[lane]; b2v = attn_b2[0];
  }

  // prologue: zero h f16 (256) + h1 f32 (128), stage x tile 0
  if (tid < 128) ((uint32_t*)lds16h)[tid] = 0u;
  if (tid < 128) lds[H1F + tid] = 0.f;
  if (tid < 256) {
    const int c = tid >> 2, t0 = (tid & 3) << 4;
    #pragma unroll
    for (int m4=0;m4<4;m4++){
      float4 v = *(const float4*)(xb + c*TS + t0 + 4*m4);
      ldsxh[(t0+4*m4+0)*XROW + c] = (f16)v.x;
      ldsxh[(t0+4*m4+1)*XROW + c] = (f16)v.y;
      ldsxh[(t0+4*m4+2)*XROW + c] = (f16)v.z;
      ldsxh[(t0+4*m4+3)*XROW + c] = (f16)v.w;
    }
  }
  __syncthreads();

  float st0R=0,st0Z=0,st0N=0, st1R=0,st1Z=0,st1N=0;  // ih-dot stash (2 rows)
  float hold0=0.f, hold1=0.f;                         // register h master
  float am=-1e30f, aZ=0.f, aP=0.f;                    // online softmax (wave 4)

  if (isGate && l==0) {
    const f16* xv = ldsxh + q16;  // x[t=0]
    float a0=0,a1=0,a2=0; dot3h(xv, Wih+0,  Wih+8,  Wih+16, a0,a1,a2); st0R=a0; st0Z=a1; st0N=a2;
    a0=0;a1=0;a2=0;       dot3h(xv, Wih+24, Wih+32, Wih+40, a0,a1,a2); st1R=a0; st1Z=a1; st1N=a2;
  }

  auto step = [&](int it_, int RB) {
    const int tile_ = it_ >> 6;
    const int xsel_ = tile_ & 1;
    const int tt_   = it_ & 63;
    if (isGate) {
      __builtin_amdgcn_s_setprio(1);
      const bool act = (l==0) ? (it_ < TS) : (it_ >= 2 && it_ <= TS+1);
      if (act) {
        const f16* hv = lds16h + hb + RB*64 + q16;
        float cr0=0,cz0=0,cn0=0, cr1=0,cz1=0,cn1=0;
        dot3h(hv, Whh+0,  Whh+8,  Whh+16, cr0,cz0,cn0);
        dot3h(hv, Whh+24, Whh+32, Whh+40, cr1,cz1,cn1);
        const float sr0=qadd2(st0R+cr0), sz0=qadd2(st0Z+cz0), xn0=qadd2(st0N), hn0=qadd2(cn0);
        const float sr1=qadd2(st1R+cr1), sz1=qadd2(st1Z+cz1), xn1=qadd2(st1N), hn1=qadd2(cn1);
        const float r0=sigmoidf_(sr0+bR0), z0=sigmoidf_(sz0+bZ0);
        const float n0=tanhf_((xn0+bI0) + r0*(hn0+bH0));
        const float r1=sigmoidf_(sr1+bR1), z1=sigmoidf_(sz1+bZ1);
        const float n1=tanhf_((xn1+bI1) + r1*(hn1+bH1));
        hold0 = n0 + z0*(hold0 - n0);   // exact in ALL quad lanes (butterfly sums)
        hold1 = n1 + z1*(hold1 - n1);
        if ((lane & 3) == 0) {
          lds16h[hb + (RB^1)*64 + row0] = (f16)hold0;
          lds16h[hb + (RB^1)*64 + row1] = (f16)hold1;
          if (l==1) {
            lds[H1F + (RB^1)*64 + row0] = hold0;
            lds[H1F + (RB^1)*64 + row1] = hold1;
          }
        }
      }
      if (l==0) {
        const int ix = it_ + 1;
        if (ix < TS) {
          const f16* xv = ldsxh + ((ix>>6)&1)*XT1F + (ix&63)*XROW + q16;
          float a0=0,a1=0,a2=0; dot3h(xv, Wih+0,  Wih+8,  Wih+16, a0,a1,a2); st0R=a0; st0Z=a1; st0N=a2;
          a0=0;a1=0;a2=0;       dot3h(xv, Wih+24, Wih+32, Wih+40, a0,a1,a2); st1R=a0; st1Z=a1; st1N=a2;
        }
      } else {
        if (it_ >= 1 && it_ <= TS) {
          const f16* gv = lds16h + RB*64 + q16;  // h0[RB] = h0(it-1)
          float a0=0,a1=0,a2=0; dot3h(gv, Wih+0,  Wih+8,  Wih+16, a0,a1,a2); st0R=a0; st0Z=a1; st0N=a2;
          a0=0;a1=0;a2=0;       dot3h(gv, Wih+24, Wih+32, Wih+40, a0,a1,a2); st1R=a0; st1Z=a1; st1N=a2;
        }
      }
      __builtin_amdgcn_s_setprio(0);
    } else if (isAttn) {
      if (it_ >= 3 && it_ <= TS+2) {
        const f16* hbp = lds16h + 128 + RB*64;
        float p0=0.f, p1=0.f, p2=0.f, p3=0.f;
        { H8 xx; xx.v8 = *(const f16x8*)(hbp+ 0);
          p0=__builtin_amdgcn_fdot2(Wih[ 0],xx.v2[0],p0,false);
          p0=__builtin_amdgcn_fdot2(Wih[ 1],xx.v2[1],p0,false);
          p0=__builtin_amdgcn_fdot2(Wih[ 2],xx.v2[2],p0,false);
          p0=__builtin_amdgcn_fdot2(Wih[ 3],xx.v2[3],p0,false);
          xx.v8 = *(const f16x8*)(hbp+ 8);
          p0=__builtin_amdgcn_fdot2(Wih[ 4],xx.v2[0],p0,false);
          p0=__builtin_amdgcn_fdot2(Wih[ 5],xx.v2[1],p0,false);
          p0=__builtin_amdgcn_fdot2(Wih[ 6],xx.v2[2],p0,false);
          p0=__builtin_amdgcn_fdot2(Wih[ 7],xx.v2[3],p0,false); }
        { H8 xx; xx.v8 = *(const f16x8*)(hbp+16);
          p1=__builtin_amdgcn_fdot2(Wih[ 8],xx.v2[0],p1,false);
          p1=__builtin_amdgcn_fdot2(Wih[ 9],xx.v2[1],p1,false);
          p1=__builtin_amdgcn_fdot2(Wih[10],xx.v2[2],p1,false);
          p1=__builtin_amdgcn_fdot2(Wih[11],xx.v2[3],p1,false);
          xx.v8 = *(const f16x8*)(hbp+24);
          p1=__builtin_amdgcn_fdot2(Wih[12],xx.v2[0],p1,false);
          p1=__builtin_amdgcn_fdot2(Wih[13],xx.v2[1],p1,false);
          p1=__builtin_amdgcn_fdot2(Wih[14],xx.v2[2],p1,false);
          p1=__builtin_amdgcn_fdot2(Wih[15],xx.v2[3],p1,false); }
        { H8 xx; xx.v8 = *(const f16x8*)(hbp+32);
          p2=__builtin_amdgcn_fdot2(Wih[16],xx.v2[0],p2,false);
          p2=__builtin_amdgcn_fdot2(Wih[17],xx.v2[1],p2,false);
          p2=__builtin_amdgcn_fdot2(Wih[18],xx.v2[2],p2,false);
          p2=__builtin_amdgcn_fdot2(Wih[19],xx.v2[3],p2,false);
          xx.v8 = *(const f16x8*)(hbp+40);
          p2=__builtin_amdgcn_fdot2(Wih[20],xx.v2[0],p2,false);
          p2=__builtin_amdgcn_fdot2(Wih[21],xx.v2[1],p2,false);
          p2=__builtin_amdgcn_fdot2(Wih[22],xx.v2[2],p2,false);
          p2=__builtin_amdgcn_fdot2(Wih[23],xx.v2[3],p2,false); }
        { H8 xx; xx.v8 = *(const f16x8*)(hbp+48);
          p3=__builtin_amdgcn_fdot2(Wih[24],xx.v2[0],p3,false);
          p3=__builtin_amdgcn_fdot2(Wih[25],xx.v2[1],p3,false);
          p3=__builtin_amdgcn_fdot2(Wih[26],xx.v2[2],p3,false);
          p3=__builtin_amdgcn_fdot2(Wih[27],xx.v2[3],p3,false);
          xx.v8 = *(const f16x8*)(hbp+56);
          p3=__builtin_amdgcn_fdot2(Wih[28],xx.v2[0],p3,false);
          p3=__builtin_amdgcn_fdot2(Wih[29],xx.v2[1],p3,false);
          p3=__builtin_amdgcn_fdot2(Wih[30],xx.v2[2],p3,false);
          p3=__builtin_amdgcn_fdot2(Wih[31],xx.v2[3],p3,false); }
        const float a  = tanhf_(((p0+p1)+(p2+p3)) + b1o);
        const float s  = wsum64(w2o * a) + b2v;
        const float h1v = lds[H1F + RB*64 + lane];
        const float mn = fmaxf(am, s);
        const float sc = __expf(am - mn);
        const float p  = __expf(s - mn);
        aZ = aZ*sc + p;
        aP = aP*sc + p*h1v;
        am = mn;
      }
    } else { // stage wave (wid 5)
      if (tile_ <= 30) {
        if (tt_ == 0) {
          const float* src = xb + (lane>>4)*TS + (tile_+1)*64 + ((lane&15)<<2);
          #pragma unroll
          for (int k=0;k<16;k++) SP[k] = *(const float4*)(src + (size_t)k*4*TS);
        } else if (tt_ == 32) {
          f16* dsth = ldsxh + (xsel_ ? 0 : XT1F);
          const int c0 = lane >> 4, t4 = (lane & 15) << 2;
          #pragma unroll
          for (int k=0;k<16;k++){
            const int cc = 4*k + c0;
            dsth[(t4+0)*XROW + cc] = (f16)SP[k].x;
            dsth[(t4+1)*XROW + cc] = (f16)SP[k].y;
            dsth[(t4+2)*XROW + cc] = (f16)SP[k].z;
            dsth[(t4+3)*XROW + cc] = (f16)SP[k].w;
          }
        }
      }
    }
    BAR();
  };

  #pragma unroll 1
  for (int itb = 0; itb < TS + 4; itb += 2) {
    step(itb,   0);
    step(itb+1, 1);
  }

  // ---------------- epilogue ----------------
  if (isAttn) {
    const float pooled = aP / aZ;
    float mu = pooled;
    #pragma unroll
    for (int m=1;m<64;m<<=1) mu += __shfl_xor(mu, m, 64);
    mu *= (1.0f/64.0f);
    const float d = pooled - mu;
    float var = d*d;
    #pragma unroll
    for (int m=1;m<64;m<<=1) var += __shfl_xor(var, m, 64);
    var *= (1.0f/64.0f);
    const float y = d * rsqrtf(var + 1e-5f) * ln_g[lane] + ln_b[lane];
    lds[SCRO + lane] = y;
  }
  __syncthreads();
  if (tid < 32) {
    const float* hw = head_w1 + tid*64;
    float acc = head_b1[tid];
    #pragma unroll
    for (int k=0;k<16;k++){
      const float4 w4 = ((const float4*)hw)[k];
      acc += w4.x*lds[SCRO+4*k+0] + w4.y*lds[SCRO+4*k+1]
           + w4.z*lds[SCRO+4*k+2] + w4.w*lds[SCRO+4*k+3];
    }
    const float u = 0.5f*acc*(1.0f + erff(acc*0.70710678118654752f)); // exact GELU
    lds[SCRO + 64 + tid] = u;
  }
  __syncthreads();
  if (tid < 8) {
    const float* hw = head_w2 + tid*32;
    float acc = head_b2[tid];
    #pragma unroll
    for (int k=0;k<8;k++){
      const float4 w4 = ((const float4*)hw)[k];
      acc += w4.x*lds[SCRO+64+4*k+0] + w4.y*lds[SCRO+64+4*k+1]
           + w4.z*lds[SCRO+64+4*k+2] + w4.w*lds[SCRO+64+4*k+3];
    }
    out[b*8 + tid] = acc;
  }
}

extern "C" void kernel_launch(void* const* d_in, const int* in_sizes, int n_in,
                              void* d_out, int out_size, void* d_ws, size_t ws_size,
                              hipStream_t stream) {
  (void)in_sizes; (void)n_in; (void)d_ws; (void)ws_size; (void)out_size;
  const float* x       = (const float*)d_in[0];
  const float* w_ih0   = (const float*)d_in[1];
  const float* w_hh0   = (const float*)d_in[2];
  const float* b_ih0   = (const float*)d_in[3];
  const float* b_hh0   = (const float*)d_in[4];
  const float* w_ih1   = (const float*)d_in[5];
  const float* w_hh1   = (const float*)d_in[6];
  const float* b_ih1   = (const float*)d_in[7];
  const float* b_hh1   = (const float*)d_in[8];
  const float* attn_w1 = (const float*)d_in[9];
  const float* attn_b1 = (const float*)d_in[10];
  const float* attn_w2 = (const float*)d_in[11];
  const float* attn_b2 = (const float*)d_in[12];
  const float* ln_g    = (const float*)d_in[13];
  const float* ln_b    = (const float*)d_in[14];
  const float* head_w1 = (const float*)d_in[15];
  const float* head_b1 = (const float*)d_in[16];
  const float* head_w2 = (const float*)d_in[17];
  const float* head_b2 = (const float*)d_in[18];
  hipLaunchKernelGGL(gru_attn_fused, dim3(256), dim3(384), 0, stream,
                     x, w_ih0, w_hh0, b_ih0, b_hh0, w_ih1, w_hh1, b_ih1, b_hh1,
                     attn_w1, attn_b1, attn_w2, attn_b2, ln_g, ln_b,
                     head_w1, head_b1, head_w2, head_b2, (float*)d_out);
}